// Round 2
// baseline (133.189 us; speedup 1.0000x reference)
//
#include <hip/hip_runtime.h>
#include <hip/hip_fp16.h>

#define RESG 128
#define NVOX (RESG * RESG * RESG)
#define NCH 28
#define NPADH 32  // halves per voxel (64 B per voxel)
#define NSAMP 444
#define NCHUNK 7

static __device__ __forceinline__ __half2 u_as_h2(unsigned int u) {
    union { unsigned int u; __half2 h; } c;
    c.u = u;
    return c.h;
}
static __device__ __forceinline__ unsigned int h2_as_u(__half2 h) {
    union { __half2 h; unsigned int u; } c;
    c.h = h;
    return c.u;
}

// Transpose [C][Z][Y][X] f32 -> [Z][Y][X][C(pad32)] fp16.
// 4 threads per voxel; each thread produces one uint4 (8 channels) so a wave's
// store instruction writes 1 KB fully contiguous.
__global__ __launch_bounds__(256) void xpose4_k(const float* __restrict__ src,
                                                __half* __restrict__ dst) {
    const int g = blockIdx.x * 256 + threadIdx.x;  // g = 4*v + q
    const int v = g >> 2;
    const int q = g & 3;
    unsigned int w[4];
#pragma unroll
    for (int j = 0; j < 4; ++j) {
        const int c0 = q * 8 + 2 * j;
        const int c1 = c0 + 1;
        const float f0 = (c0 < NCH) ? src[(size_t)c0 * NVOX + v] : 0.0f;
        const float f1 = (c1 < NCH) ? src[(size_t)c1 * NVOX + v] : 0.0f;
        w[j] = h2_as_u(__floats2half2_rn(f0, f1));
    }
    reinterpret_cast<uint4*>(dst)[(size_t)g] = make_uint4(w[0], w[1], w[2], w[3]);
}

// Block = 128 threads = 1 ray x 2 waves. Wave w owns chunks {w, w+2, w+4, ...}.
// Each chunk (64 samples) produces independent (sumRGBA, prod(1-alpha)) composed
// in chunk order by thread 0 at the end (segmented-scan associativity).
template <bool TR>
__global__ __launch_bounds__(128) void render2_k(const float* __restrict__ ro,
                                                 const float* __restrict__ rd,
                                                 const void* __restrict__ gptr,
                                                 float* __restrict__ out, int B) {
    const int ray = blockIdx.x;
    if (ray >= B) return;
    const int wid = (int)(threadIdx.x >> 6);
    const int lane = (int)(threadIdx.x & 63);

    __shared__ float sres[NCHUNK][5];
    if (threadIdx.x < NCHUNK) {
        sres[threadIdx.x][0] = 0.0f;
        sres[threadIdx.x][1] = 0.0f;
        sres[threadIdx.x][2] = 0.0f;
        sres[threadIdx.x][3] = 0.0f;
        sres[threadIdx.x][4] = 1.0f;
    }
    __syncthreads();

    const float RAD = 1.3f;
    const float STEPF = (float)(1.3 * 2.0 / 128.0 / 2.0);

    const float ox = ro[ray * 3 + 0], oy = ro[ray * 3 + 1], oz = ro[ray * 3 + 2];
    const float dxr = rd[ray * 3 + 0], dyr = rd[ray * 3 + 1], dzr = rd[ray * 3 + 2];

    const float ivx = 1.0f / dxr, ivy = 1.0f / dyr, ivz = 1.0f / dzr;
    const float t0x = (-RAD - ox) * ivx, t1x = (RAD - ox) * ivx;
    const float t0y = (-RAD - oy) * ivy, t1y = (RAD - oy) * ivy;
    const float t0z = (-RAD - oz) * ivz, t1z = (RAD - oz) * ivz;
    float tmin = fmaxf(fmaxf(fminf(t0x, t1x), fminf(t0y, t1y)), fminf(t0z, t1z));
    tmin = fmaxf(tmin, 0.0f);
    const float tmax = fminf(fminf(fmaxf(t0x, t1x), fmaxf(t0y, t1y)), fmaxf(t0z, t1z));

    const float nrm = sqrtf(dxr * dxr + dyr * dyr + dzr * dzr);
    const float dist = STEPF * nrm;

    const float inn = 1.0f / (nrm + 1e-9f);
    const float x = dxr * inn, y = dyr * inn, z = dzr * inn;
    float sh[9];
    sh[0] = 0.28209479177387814f;
    sh[1] = -0.4886025119029199f * y;
    sh[2] = 0.4886025119029199f * z;
    sh[3] = -0.4886025119029199f * x;
    sh[4] = 1.0925484305920792f * x * y;
    sh[5] = -1.0925484305920792f * y * z;
    sh[6] = 0.31539156525252005f * (2.0f * z * z - x * x - y * y);
    sh[7] = -1.0925484305920792f * x * z;
    sh[8] = 0.5462742152960396f * (x * x - y * y);

    if (tmin < tmax) {
        for (int c = wid; c < NCHUNK; c += 2) {
            const float tb = tmin + (float)(c * 64) * STEPF;
            if (tb >= tmax) break;  // wave-uniform; later chunks of this wave also dead

            const int sidx = c * 64 + lane;
            const float t = tmin + (float)sidx * STEPF;
            const float px = ox + dxr * t, py = oy + dyr * t, pz = oz + dzr * t;
            const bool live = (sidx < NSAMP) && (t < tmax) && (fabsf(px) <= RAD) &&
                              (fabsf(py) <= RAD) && (fabsf(pz) <= RAD);
            float alpha = 0.f, cr = 0.f, cg = 0.f, cb = 0.f;
            if (live) {
                float gx = fminf(fmaxf((px / RAD + 1.0f) * 0.5f * 127.0f, 0.0f), 127.0f);
                float gy = fminf(fmaxf((py / RAD + 1.0f) * 0.5f * 127.0f, 0.0f), 127.0f);
                float gz = fminf(fmaxf((pz / RAD + 1.0f) * 0.5f * 127.0f, 0.0f), 127.0f);
                const int x0 = min((int)gx, 126);
                const int y0 = min((int)gy, 126);
                const int z0 = min((int)gz, 126);
                const float fx = gx - (float)x0;
                const float fy = gy - (float)y0;
                const float fz = gz - (float)z0;
                float f[NCH];
                if constexpr (TR) {
                    const __half* gbuf = (const __half*)gptr;
                    const size_t base = (size_t)((z0 * RESG + y0) * RESG + x0) * NPADH;
                    __half2 a2[14];
#pragma unroll
                    for (int j = 0; j < 14; ++j) a2[j] = __float2half2_rn(0.0f);
#pragma unroll
                    for (int c8 = 0; c8 < 8; ++c8) {
                        const int dzi = c8 >> 2, dyi = (c8 >> 1) & 1, dxi = c8 & 1;
                        const float wgt = (dzi ? fz : 1.0f - fz) * (dyi ? fy : 1.0f - fy) *
                                          (dxi ? fx : 1.0f - fx);
                        const __half* cp = gbuf + base + dzi * (RESG * RESG * NPADH) +
                                           dyi * (RESG * NPADH) + dxi * NPADH;
                        const uint4 q0 = *reinterpret_cast<const uint4*>(cp);
                        const uint4 q1 = *reinterpret_cast<const uint4*>(cp + 8);
                        const uint4 q2 = *reinterpret_cast<const uint4*>(cp + 16);
                        const uint2 q3 = *reinterpret_cast<const uint2*>(cp + 24);
                        const __half2 wh = __float2half2_rn(wgt);
                        a2[0] = __hfma2(u_as_h2(q0.x), wh, a2[0]);
                        a2[1] = __hfma2(u_as_h2(q0.y), wh, a2[1]);
                        a2[2] = __hfma2(u_as_h2(q0.z), wh, a2[2]);
                        a2[3] = __hfma2(u_as_h2(q0.w), wh, a2[3]);
                        a2[4] = __hfma2(u_as_h2(q1.x), wh, a2[4]);
                        a2[5] = __hfma2(u_as_h2(q1.y), wh, a2[5]);
                        a2[6] = __hfma2(u_as_h2(q1.z), wh, a2[6]);
                        a2[7] = __hfma2(u_as_h2(q1.w), wh, a2[7]);
                        a2[8] = __hfma2(u_as_h2(q2.x), wh, a2[8]);
                        a2[9] = __hfma2(u_as_h2(q2.y), wh, a2[9]);
                        a2[10] = __hfma2(u_as_h2(q2.z), wh, a2[10]);
                        a2[11] = __hfma2(u_as_h2(q2.w), wh, a2[11]);
                        a2[12] = __hfma2(u_as_h2(q3.x), wh, a2[12]);
                        a2[13] = __hfma2(u_as_h2(q3.y), wh, a2[13]);
                    }
#pragma unroll
                    for (int j = 0; j < 14; ++j) {
                        const float2 t2 = __half22float2(a2[j]);
                        f[2 * j] = t2.x;
                        f[2 * j + 1] = t2.y;
                    }
                } else {
                    const float* gf = (const float*)gptr;
                    const size_t cell = (size_t)(z0 * RESG + y0) * RESG + x0;
#pragma unroll
                    for (int cc = 0; cc < NCH; ++cc) f[cc] = 0.0f;
#pragma unroll
                    for (int c8 = 0; c8 < 8; ++c8) {
                        const int dzi = c8 >> 2, dyi = (c8 >> 1) & 1, dxi = c8 & 1;
                        const float wgt = (dzi ? fz : 1.0f - fz) * (dyi ? fy : 1.0f - fy) *
                                          (dxi ? fx : 1.0f - fx);
                        const float* p = gf + cell + dzi * (RESG * RESG) + dyi * RESG + dxi;
#pragma unroll
                        for (int cc = 0; cc < NCH; ++cc) f[cc] += wgt * p[(size_t)cc * NVOX];
                    }
                }
                const float sigma = fmaxf(f[27], 0.0f);
                float r = 0.f, g = 0.f, b = 0.f;
#pragma unroll
                for (int k = 0; k < 9; ++k) {
                    r += sh[k] * f[k];
                    g += sh[k] * f[9 + k];
                    b += sh[k] * f[18 + k];
                }
                alpha = 1.0f - __expf(-sigma * dist);
                cr = 1.0f / (1.0f + __expf(-r));
                cg = 1.0f / (1.0f + __expf(-g));
                cb = 1.0f / (1.0f + __expf(-b));
            }
            // chunk-local exclusive prefix product of (1-alpha+1e-10)
            const float wfac = 1.0f - alpha + 1e-10f;
            float incl = wfac;
#pragma unroll
            for (int off = 1; off < 64; off <<= 1) {
                const float u = __shfl_up(incl, off);
                if (lane >= off) incl *= u;
            }
            float excl = __shfl_up(incl, 1);
            if (lane == 0) excl = 1.0f;
            const float al = alpha * excl;
            float pR = al * cr, pG = al * cg, pB = al * cb, pA = al;
#pragma unroll
            for (int off = 32; off; off >>= 1) {
                pR += __shfl_xor(pR, off);
                pG += __shfl_xor(pG, off);
                pB += __shfl_xor(pB, off);
                pA += __shfl_xor(pA, off);
            }
            const float Pc = __shfl(incl, 63);
            if (lane == 0) {
                sres[c][0] = pR;
                sres[c][1] = pG;
                sres[c][2] = pB;
                sres[c][3] = pA;
                sres[c][4] = Pc;
            }
        }
    }
    __syncthreads();
    if (threadIdx.x == 0) {
        float T = 1.0f, R = 0.f, G = 0.f, Bl = 0.f, A = 0.f;
#pragma unroll
        for (int c = 0; c < NCHUNK; ++c) {
            R += T * sres[c][0];
            G += T * sres[c][1];
            Bl += T * sres[c][2];
            A += T * sres[c][3];
            T *= sres[c][4];
        }
        const float bg = 1.0f - A;
        out[ray * 3 + 0] = R + bg;
        out[ray * 3 + 1] = G + bg;
        out[ray * 3 + 2] = Bl + bg;
    }
}

extern "C" void kernel_launch(void* const* d_in, const int* in_sizes, int n_in,
                              void* d_out, int out_size, void* d_ws, size_t ws_size,
                              hipStream_t stream) {
    const float* rays_o = (const float*)d_in[0];
    const float* rays_d = (const float*)d_in[1];
    const float* data = (const float*)d_in[2];
    float* out = (float*)d_out;
    const int B = in_sizes[0] / 3;

    const size_t need = (size_t)NVOX * NPADH * sizeof(__half);  // 128 MiB

    if (d_ws != nullptr && ws_size >= need) {
        __half* grid16 = (__half*)d_ws;
        xpose4_k<<<(NVOX * 4) / 256, 256, 0, stream>>>(data, grid16);
        render2_k<true><<<B, 128, 0, stream>>>(rays_o, rays_d, (const void*)grid16, out, B);
    } else {
        render2_k<false><<<B, 128, 0, stream>>>(rays_o, rays_d, (const void*)data, out, B);
    }
}

// Round 3
// 100.891 us; speedup vs baseline: 1.3201x; 1.3201x over previous
//
#include <hip/hip_runtime.h>
#include <hip/hip_fp16.h>

#define RESG 128
#define NVOX (RESG * RESG * RESG)
#define NCH 28
#define NSAMP 444
#define NCHUNK 7

typedef float f32x2 __attribute__((ext_vector_type(2)));

#if __has_builtin(__builtin_amdgcn_cvt_pk_f32_fp8) && __has_builtin(__builtin_amdgcn_cvt_pk_fp8_f32)
#define HW_FP8 1
#else
#define HW_FP8 0
#endif

// ---------- OCP e4m3fn software fallbacks (only compiled if no HW cvt) ----------
static __device__ __forceinline__ float dec1_sw(unsigned int b) {
    unsigned int m = b & 0x7Fu;
    union { unsigned int u; float f; } c;
    c.u = (m << 20) + (120u << 23);
    float r = (m >= 8u) ? c.f : (float)m * 0.001953125f;  // denormal: m * 2^-9
    return (b & 0x80u) ? -r : r;
}
static __device__ __forceinline__ unsigned int enc1_sw(float f) {
    union { float f; unsigned int u; } c;
    c.f = f;
    unsigned int s = (c.u >> 24) & 0x80u;
    float a = fabsf(f);
    unsigned int r;
    if (a >= 0.015625f) {
        union { float f; unsigned int u; } d;
        d.f = fminf(a, 448.0f);
        unsigned int ua = d.u;
        unsigned int t = ua + 0x7FFFFu + ((ua >> 20) & 1u);  // RNE on bit 20
        r = (t >> 20) - 960u;
        r = r > 0x7Eu ? 0x7Eu : r;
    } else {
        r = (unsigned int)__float2int_rn(a * 512.0f);  // denormals (incl. m=8 -> min normal)
    }
    return s | r;
}

template <bool HI>
static __device__ __forceinline__ f32x2 dec2(unsigned int dw) {
#if HW_FP8
    return __builtin_amdgcn_cvt_pk_f32_fp8((int)dw, HI);
#else
    unsigned int w = HI ? (dw >> 16) : (dw & 0xFFFFu);
    f32x2 r;
    r.x = dec1_sw(w & 0xFFu);
    r.y = dec1_sw((w >> 8) & 0xFFu);
    return r;
#endif
}
template <bool HI>
static __device__ __forceinline__ unsigned int pack2(float a, float b, unsigned int old) {
#if HW_FP8
    return (unsigned int)__builtin_amdgcn_cvt_pk_fp8_f32(a, b, (int)old, HI);
#else
    unsigned int w = enc1_sw(a) | (enc1_sw(b) << 8);
    return HI ? ((old & 0x0000FFFFu) | (w << 16)) : ((old & 0xFFFF0000u) | w);
#endif
}

// Pack [C][Z][Y][X] f32 -> [Z][Y][X] voxels of 32B: 27 x fp8 SH, pad, fp16 sigma.
__global__ __launch_bounds__(256) void pack_k(const float* __restrict__ src,
                                              uint4* __restrict__ dst) {
    const int v = blockIdx.x * 256 + threadIdx.x;
    float vals[NCH];
#pragma unroll
    for (int c = 0; c < NCH; ++c) vals[c] = src[(size_t)c * NVOX + v];
    unsigned int d[8];
#pragma unroll
    for (int j = 0; j < 6; ++j) {
        unsigned int t = pack2<false>(vals[4 * j], vals[4 * j + 1], 0u);
        d[j] = pack2<true>(vals[4 * j + 2], vals[4 * j + 3], t);
    }
    {
        unsigned int t = pack2<false>(vals[24], vals[25], 0u);
        d[6] = pack2<true>(vals[26], 0.0f, t);
    }
    union { __half h; unsigned short u; } sg;
    sg.h = __float2half(vals[27]);
    d[7] = (unsigned int)sg.u;
    dst[2 * (size_t)v] = make_uint4(d[0], d[1], d[2], d[3]);
    dst[2 * (size_t)v + 1] = make_uint4(d[4], d[5], d[6], d[7]);
}

// Block = 128 threads = 1 ray x 2 waves. Wave w owns chunks {w, w+2, ...}.
// Chunk results composed in order via LDS (segmented associativity).
template <bool TR>
__global__ __launch_bounds__(128) void render3_k(const float* __restrict__ ro,
                                                 const float* __restrict__ rd,
                                                 const void* __restrict__ gptr,
                                                 float* __restrict__ out, int B) {
    const int ray = blockIdx.x;
    if (ray >= B) return;
    const int wid = (int)(threadIdx.x >> 6);
    const int lane = (int)(threadIdx.x & 63);

    __shared__ float sres[NCHUNK][5];
    if (threadIdx.x < NCHUNK) {
        sres[threadIdx.x][0] = 0.0f;
        sres[threadIdx.x][1] = 0.0f;
        sres[threadIdx.x][2] = 0.0f;
        sres[threadIdx.x][3] = 0.0f;
        sres[threadIdx.x][4] = 1.0f;
    }
    __syncthreads();

    const float RAD = 1.3f;
    const float STEPF = (float)(1.3 * 2.0 / 128.0 / 2.0);

    const float ox = ro[ray * 3 + 0], oy = ro[ray * 3 + 1], oz = ro[ray * 3 + 2];
    const float dxr = rd[ray * 3 + 0], dyr = rd[ray * 3 + 1], dzr = rd[ray * 3 + 2];

    const float ivx = 1.0f / dxr, ivy = 1.0f / dyr, ivz = 1.0f / dzr;
    const float t0x = (-RAD - ox) * ivx, t1x = (RAD - ox) * ivx;
    const float t0y = (-RAD - oy) * ivy, t1y = (RAD - oy) * ivy;
    const float t0z = (-RAD - oz) * ivz, t1z = (RAD - oz) * ivz;
    float tmin = fmaxf(fmaxf(fminf(t0x, t1x), fminf(t0y, t1y)), fminf(t0z, t1z));
    tmin = fmaxf(tmin, 0.0f);
    const float tmax = fminf(fminf(fmaxf(t0x, t1x), fmaxf(t0y, t1y)), fmaxf(t0z, t1z));

    const float nrm = sqrtf(dxr * dxr + dyr * dyr + dzr * dzr);
    const float dist = STEPF * nrm;

    const float inn = 1.0f / (nrm + 1e-9f);
    const float x = dxr * inn, y = dyr * inn, z = dzr * inn;
    float sh[9];
    sh[0] = 0.28209479177387814f;
    sh[1] = -0.4886025119029199f * y;
    sh[2] = 0.4886025119029199f * z;
    sh[3] = -0.4886025119029199f * x;
    sh[4] = 1.0925484305920792f * x * y;
    sh[5] = -1.0925484305920792f * y * z;
    sh[6] = 0.31539156525252005f * (2.0f * z * z - x * x - y * y);
    sh[7] = -1.0925484305920792f * x * z;
    sh[8] = 0.5462742152960396f * (x * x - y * y);

    if (tmin < tmax) {
        for (int c = wid; c < NCHUNK; c += 2) {
            const float tb = tmin + (float)(c * 64) * STEPF;
            if (tb >= tmax) break;  // wave-uniform

            const int sidx = c * 64 + lane;
            const float t = tmin + (float)sidx * STEPF;
            const float px = ox + dxr * t, py = oy + dyr * t, pz = oz + dzr * t;
            const bool live = (sidx < NSAMP) && (t < tmax) && (fabsf(px) <= RAD) &&
                              (fabsf(py) <= RAD) && (fabsf(pz) <= RAD);
            float alpha = 0.f, cr = 0.f, cg = 0.f, cb = 0.f;
            if (live) {
                float gx = fminf(fmaxf((px / RAD + 1.0f) * 0.5f * 127.0f, 0.0f), 127.0f);
                float gy = fminf(fmaxf((py / RAD + 1.0f) * 0.5f * 127.0f, 0.0f), 127.0f);
                float gz = fminf(fmaxf((pz / RAD + 1.0f) * 0.5f * 127.0f, 0.0f), 127.0f);
                const int x0 = min((int)gx, 126);
                const int y0 = min((int)gy, 126);
                const int z0 = min((int)gz, 126);
                const float fx = gx - (float)x0;
                const float fy = gy - (float)y0;
                const float fz = gz - (float)z0;
                float f[NCH];
#pragma unroll
                for (int cc = 0; cc < NCH; ++cc) f[cc] = 0.0f;

                float wc[8];
#pragma unroll
                for (int c8 = 0; c8 < 8; ++c8) {
                    wc[c8] = ((c8 & 4) ? fz : 1.0f - fz) * ((c8 & 2) ? fy : 1.0f - fy) *
                             ((c8 & 1) ? fx : 1.0f - fx);
                }

                if constexpr (TR) {
                    const uint4* gb = (const uint4*)gptr;
                    const unsigned int cell = (unsigned int)((z0 * RESG + y0) * RESG + x0);
#pragma unroll
                    for (int g = 0; g < 2; ++g) {
                        uint4 qa[4], qb[4];
#pragma unroll
                        for (int k = 0; k < 4; ++k) {
                            const int c8 = g * 4 + k;
                            const unsigned int vi = cell + ((c8 >> 2) & 1) * (RESG * RESG) +
                                                    ((c8 >> 1) & 1) * RESG + (c8 & 1);
                            qa[k] = gb[2 * (size_t)vi];
                            qb[k] = gb[2 * (size_t)vi + 1];
                        }
#pragma unroll
                        for (int k = 0; k < 4; ++k) {
                            const float w = wc[g * 4 + k];
                            f32x2 p;
                            p = dec2<false>(qa[k].x); f[0] += w * p.x;  f[1] += w * p.y;
                            p = dec2<true >(qa[k].x); f[2] += w * p.x;  f[3] += w * p.y;
                            p = dec2<false>(qa[k].y); f[4] += w * p.x;  f[5] += w * p.y;
                            p = dec2<true >(qa[k].y); f[6] += w * p.x;  f[7] += w * p.y;
                            p = dec2<false>(qa[k].z); f[8] += w * p.x;  f[9] += w * p.y;
                            p = dec2<true >(qa[k].z); f[10] += w * p.x; f[11] += w * p.y;
                            p = dec2<false>(qa[k].w); f[12] += w * p.x; f[13] += w * p.y;
                            p = dec2<true >(qa[k].w); f[14] += w * p.x; f[15] += w * p.y;
                            p = dec2<false>(qb[k].x); f[16] += w * p.x; f[17] += w * p.y;
                            p = dec2<true >(qb[k].x); f[18] += w * p.x; f[19] += w * p.y;
                            p = dec2<false>(qb[k].y); f[20] += w * p.x; f[21] += w * p.y;
                            p = dec2<true >(qb[k].y); f[22] += w * p.x; f[23] += w * p.y;
                            p = dec2<false>(qb[k].z); f[24] += w * p.x; f[25] += w * p.y;
                            p = dec2<true >(qb[k].z); f[26] += w * p.x;
                            union { unsigned short u; __half h; } sg;
                            sg.u = (unsigned short)(qb[k].w & 0xFFFFu);
                            f[27] += w * __half2float(sg.h);
                        }
                    }
                } else {
                    const float* gf = (const float*)gptr;
                    const size_t cell = (size_t)(z0 * RESG + y0) * RESG + x0;
#pragma unroll
                    for (int c8 = 0; c8 < 8; ++c8) {
                        const float w = wc[c8];
                        const float* p = gf + cell + ((c8 >> 2) & 1) * (RESG * RESG) +
                                         ((c8 >> 1) & 1) * RESG + (c8 & 1);
#pragma unroll
                        for (int cc = 0; cc < NCH; ++cc) f[cc] += w * p[(size_t)cc * NVOX];
                    }
                }
                const float sigma = fmaxf(f[27], 0.0f);
                float r = 0.f, g = 0.f, b = 0.f;
#pragma unroll
                for (int k = 0; k < 9; ++k) {
                    r += sh[k] * f[k];
                    g += sh[k] * f[9 + k];
                    b += sh[k] * f[18 + k];
                }
                alpha = 1.0f - __expf(-sigma * dist);
                cr = 1.0f / (1.0f + __expf(-r));
                cg = 1.0f / (1.0f + __expf(-g));
                cb = 1.0f / (1.0f + __expf(-b));
            }
            const float wfac = 1.0f - alpha + 1e-10f;
            float incl = wfac;
#pragma unroll
            for (int off = 1; off < 64; off <<= 1) {
                const float u = __shfl_up(incl, off);
                if (lane >= off) incl *= u;
            }
            float excl = __shfl_up(incl, 1);
            if (lane == 0) excl = 1.0f;
            const float al = alpha * excl;
            float pR = al * cr, pG = al * cg, pB = al * cb, pA = al;
#pragma unroll
            for (int off = 32; off; off >>= 1) {
                pR += __shfl_xor(pR, off);
                pG += __shfl_xor(pG, off);
                pB += __shfl_xor(pB, off);
                pA += __shfl_xor(pA, off);
            }
            const float Pc = __shfl(incl, 63);
            if (lane == 0) {
                sres[c][0] = pR;
                sres[c][1] = pG;
                sres[c][2] = pB;
                sres[c][3] = pA;
                sres[c][4] = Pc;
            }
        }
    }
    __syncthreads();
    if (threadIdx.x == 0) {
        float T = 1.0f, R = 0.f, G = 0.f, Bl = 0.f, A = 0.f;
#pragma unroll
        for (int c = 0; c < NCHUNK; ++c) {
            R += T * sres[c][0];
            G += T * sres[c][1];
            Bl += T * sres[c][2];
            A += T * sres[c][3];
            T *= sres[c][4];
        }
        const float bg = 1.0f - A;
        out[ray * 3 + 0] = R + bg;
        out[ray * 3 + 1] = G + bg;
        out[ray * 3 + 2] = Bl + bg;
    }
}

extern "C" void kernel_launch(void* const* d_in, const int* in_sizes, int n_in,
                              void* d_out, int out_size, void* d_ws, size_t ws_size,
                              hipStream_t stream) {
    const float* rays_o = (const float*)d_in[0];
    const float* rays_d = (const float*)d_in[1];
    const float* data = (const float*)d_in[2];
    float* out = (float*)d_out;
    const int B = in_sizes[0] / 3;

    const size_t need = (size_t)NVOX * 32;  // 64 MiB packed grid

    if (d_ws != nullptr && ws_size >= need) {
        uint4* gridp = (uint4*)d_ws;
        pack_k<<<NVOX / 256, 256, 0, stream>>>(data, gridp);
        render3_k<true><<<B, 128, 0, stream>>>(rays_o, rays_d, (const void*)gridp, out, B);
    } else {
        render3_k<false><<<B, 128, 0, stream>>>(rays_o, rays_d, (const void*)data, out, B);
    }
}

// Round 4
// 82.214 us; speedup vs baseline: 1.6200x; 1.2272x over previous
//
#include <hip/hip_runtime.h>
#include <hip/hip_fp16.h>

#define RESG 128
#define NVOX (RESG * RESG * RESG)
#define NCH 28
#define NSAMP 444
#define NCHUNK 7

typedef float f32x2 __attribute__((ext_vector_type(2)));

#if __has_builtin(__builtin_amdgcn_cvt_scalef32_pk_f32_fp4)
#define HW_DEC4 1
#else
#define HW_DEC4 0
#endif

// ---- e2m1 helpers. Grid values are pre-scaled x32 at pack time; render folds
// ---- the x(1/32) into the trilinear weight, so HW scale operand is 1.0 (neutral).
static __device__ __forceinline__ float dec_nib(unsigned int n) {
    const unsigned int em = n & 7u;
    float mag;
    if (em < 2u) {
        mag = 0.5f * (float)em;
    } else {
        union { unsigned int u; float f; } c;
        c.u = (((em >> 1) + 126u) << 23) | ((em & 1u) << 22);
        mag = c.f;
    }
    return (n & 8u) ? -mag : mag;
}
template <int SEL>
static __device__ __forceinline__ f32x2 dec4(unsigned int dw) {
#if HW_DEC4
    return __builtin_amdgcn_cvt_scalef32_pk_f32_fp4(dw, 1.0f, SEL);
#else
    const unsigned int b = (dw >> (8 * SEL)) & 0xFFu;
    f32x2 r;
    r.x = dec_nib(b & 15u);
    r.y = dec_nib(b >> 4);
    return r;
#endif
}
static __device__ __forceinline__ unsigned int enc_nib(float f) {
    const unsigned int s = (__float_as_uint(f) >> 28) & 8u;
    const float a = fabsf(f);
    unsigned int em;
    if (a < 1.75f) em = (unsigned int)__float2int_rn(a * 2.0f);
    else if (a < 2.5f) em = 4u;
    else if (a < 3.5f) em = 5u;
    else if (a < 5.0f) em = 6u;
    else em = 7u;
    return s | em;
}
static __device__ __forceinline__ unsigned int enc_pair(float a, float b) {
    return enc_nib(a) | (enc_nib(b) << 4);
}

// Pack [C][Z][Y][X] f32 -> 16B voxels: 27 x e2m1 (x32 scaled), fp16 sigma.
__global__ __launch_bounds__(256) void pack4_k(const float* __restrict__ src,
                                               uint4* __restrict__ dst) {
    const int v = blockIdx.x * 256 + threadIdx.x;
    float s[NCH];
#pragma unroll
    for (int c = 0; c < NCH; ++c) s[c] = src[(size_t)c * NVOX + v];
#pragma unroll
    for (int c = 0; c < 27; ++c) s[c] *= 32.0f;
    unsigned int d[4];
#pragma unroll
    for (int j = 0; j < 3; ++j) {
        d[j] = enc_pair(s[8 * j + 0], s[8 * j + 1]) |
               (enc_pair(s[8 * j + 2], s[8 * j + 3]) << 8) |
               (enc_pair(s[8 * j + 4], s[8 * j + 5]) << 16) |
               (enc_pair(s[8 * j + 6], s[8 * j + 7]) << 24);
    }
    union { __half h; unsigned short u; } sg;
    sg.h = __float2half(s[27]);
    d[3] = enc_pair(s[24], s[25]) | (enc_pair(s[26], 0.0f) << 8) |
           ((unsigned int)sg.u << 16);
    dst[(size_t)v] = make_uint4(d[0], d[1], d[2], d[3]);
}

// Block = 128 threads = 1 ray x 2 waves; wave w owns chunks {w, w+2, ...};
// per-chunk (sumRGBA, prod(1-alpha)) composed in order via LDS.
template <bool TR>
__global__ __launch_bounds__(128) void render4_k(const float* __restrict__ ro,
                                                 const float* __restrict__ rd,
                                                 const void* __restrict__ gptr,
                                                 float* __restrict__ out, int B) {
    const int ray = blockIdx.x;
    if (ray >= B) return;
    const int wid = (int)(threadIdx.x >> 6);
    const int lane = (int)(threadIdx.x & 63);

    __shared__ float sres[NCHUNK][5];
    if (threadIdx.x < NCHUNK) {
        sres[threadIdx.x][0] = 0.0f;
        sres[threadIdx.x][1] = 0.0f;
        sres[threadIdx.x][2] = 0.0f;
        sres[threadIdx.x][3] = 0.0f;
        sres[threadIdx.x][4] = 1.0f;
    }
    __syncthreads();

    const float RAD = 1.3f;
    const float STEPF = (float)(1.3 * 2.0 / 128.0 / 2.0);

    const float ox = ro[ray * 3 + 0], oy = ro[ray * 3 + 1], oz = ro[ray * 3 + 2];
    const float dxr = rd[ray * 3 + 0], dyr = rd[ray * 3 + 1], dzr = rd[ray * 3 + 2];

    const float ivx = 1.0f / dxr, ivy = 1.0f / dyr, ivz = 1.0f / dzr;
    const float t0x = (-RAD - ox) * ivx, t1x = (RAD - ox) * ivx;
    const float t0y = (-RAD - oy) * ivy, t1y = (RAD - oy) * ivy;
    const float t0z = (-RAD - oz) * ivz, t1z = (RAD - oz) * ivz;
    float tmin = fmaxf(fmaxf(fminf(t0x, t1x), fminf(t0y, t1y)), fminf(t0z, t1z));
    tmin = fmaxf(tmin, 0.0f);
    const float tmax = fminf(fminf(fmaxf(t0x, t1x), fmaxf(t0y, t1y)), fmaxf(t0z, t1z));

    const float nrm = sqrtf(dxr * dxr + dyr * dyr + dzr * dzr);
    const float dist = STEPF * nrm;

    const float inn = 1.0f / (nrm + 1e-9f);
    const float x = dxr * inn, y = dyr * inn, z = dzr * inn;
    float sh[9];
    sh[0] = 0.28209479177387814f;
    sh[1] = -0.4886025119029199f * y;
    sh[2] = 0.4886025119029199f * z;
    sh[3] = -0.4886025119029199f * x;
    sh[4] = 1.0925484305920792f * x * y;
    sh[5] = -1.0925484305920792f * y * z;
    sh[6] = 0.31539156525252005f * (2.0f * z * z - x * x - y * y);
    sh[7] = -1.0925484305920792f * x * z;
    sh[8] = 0.5462742152960396f * (x * x - y * y);

    if (tmin < tmax) {
        for (int c = wid; c < NCHUNK; c += 2) {
            const float tb = tmin + (float)(c * 64) * STEPF;
            if (tb >= tmax) break;  // wave-uniform

            const int sidx = c * 64 + lane;
            const float t = tmin + (float)sidx * STEPF;
            const float px = ox + dxr * t, py = oy + dyr * t, pz = oz + dzr * t;
            const bool live = (sidx < NSAMP) && (t < tmax) && (fabsf(px) <= RAD) &&
                              (fabsf(py) <= RAD) && (fabsf(pz) <= RAD);
            float alpha = 0.f, cr = 0.f, cg = 0.f, cb = 0.f;
            if (live) {
                float gx = fminf(fmaxf((px / RAD + 1.0f) * 0.5f * 127.0f, 0.0f), 127.0f);
                float gy = fminf(fmaxf((py / RAD + 1.0f) * 0.5f * 127.0f, 0.0f), 127.0f);
                float gz = fminf(fmaxf((pz / RAD + 1.0f) * 0.5f * 127.0f, 0.0f), 127.0f);
                const int x0 = min((int)gx, 126);
                const int y0 = min((int)gy, 126);
                const int z0 = min((int)gz, 126);
                const float fx = gx - (float)x0;
                const float fy = gy - (float)y0;
                const float fz = gz - (float)z0;
                float f[NCH];
#pragma unroll
                for (int cc = 0; cc < NCH; ++cc) f[cc] = 0.0f;

                float wc[8];
#pragma unroll
                for (int c8 = 0; c8 < 8; ++c8) {
                    wc[c8] = ((c8 & 4) ? fz : 1.0f - fz) * ((c8 & 2) ? fy : 1.0f - fy) *
                             ((c8 & 1) ? fx : 1.0f - fx);
                }

                if constexpr (TR) {
                    const uint4* gb = (const uint4*)gptr;
                    const unsigned int cell = (unsigned int)((z0 * RESG + y0) * RESG + x0);
#pragma unroll
                    for (int g = 0; g < 2; ++g) {
                        uint4 q[4];
#pragma unroll
                        for (int k = 0; k < 4; ++k) {
                            const int c8 = g * 4 + k;
                            const unsigned int vi = cell + ((c8 >> 2) & 1) * (RESG * RESG) +
                                                    ((c8 >> 1) & 1) * RESG + (c8 & 1);
                            q[k] = gb[(size_t)vi];
                        }
#pragma unroll
                        for (int k = 0; k < 4; ++k) {
                            const float w = wc[g * 4 + k];
                            const float ws = w * 0.03125f;
                            f32x2 p;
                            p = dec4<0>(q[k].x); f[0] += ws * p.x;  f[1] += ws * p.y;
                            p = dec4<1>(q[k].x); f[2] += ws * p.x;  f[3] += ws * p.y;
                            p = dec4<2>(q[k].x); f[4] += ws * p.x;  f[5] += ws * p.y;
                            p = dec4<3>(q[k].x); f[6] += ws * p.x;  f[7] += ws * p.y;
                            p = dec4<0>(q[k].y); f[8] += ws * p.x;  f[9] += ws * p.y;
                            p = dec4<1>(q[k].y); f[10] += ws * p.x; f[11] += ws * p.y;
                            p = dec4<2>(q[k].y); f[12] += ws * p.x; f[13] += ws * p.y;
                            p = dec4<3>(q[k].y); f[14] += ws * p.x; f[15] += ws * p.y;
                            p = dec4<0>(q[k].z); f[16] += ws * p.x; f[17] += ws * p.y;
                            p = dec4<1>(q[k].z); f[18] += ws * p.x; f[19] += ws * p.y;
                            p = dec4<2>(q[k].z); f[20] += ws * p.x; f[21] += ws * p.y;
                            p = dec4<3>(q[k].z); f[22] += ws * p.x; f[23] += ws * p.y;
                            p = dec4<0>(q[k].w); f[24] += ws * p.x; f[25] += ws * p.y;
                            p = dec4<1>(q[k].w); f[26] += ws * p.x;
                            union { unsigned short u; __half h; } sg;
                            sg.u = (unsigned short)(q[k].w >> 16);
                            f[27] += w * __half2float(sg.h);
                        }
                    }
                } else {
                    const float* gf = (const float*)gptr;
                    const size_t cell = (size_t)(z0 * RESG + y0) * RESG + x0;
#pragma unroll
                    for (int c8 = 0; c8 < 8; ++c8) {
                        const float w = wc[c8];
                        const float* p = gf + cell + ((c8 >> 2) & 1) * (RESG * RESG) +
                                         ((c8 >> 1) & 1) * RESG + (c8 & 1);
#pragma unroll
                        for (int cc = 0; cc < NCH; ++cc) f[cc] += w * p[(size_t)cc * NVOX];
                    }
                }
                const float sigma = fmaxf(f[27], 0.0f);
                float r = 0.f, g = 0.f, b = 0.f;
#pragma unroll
                for (int k = 0; k < 9; ++k) {
                    r += sh[k] * f[k];
                    g += sh[k] * f[9 + k];
                    b += sh[k] * f[18 + k];
                }
                alpha = 1.0f - __expf(-sigma * dist);
                cr = 1.0f / (1.0f + __expf(-r));
                cg = 1.0f / (1.0f + __expf(-g));
                cb = 1.0f / (1.0f + __expf(-b));
            }
            const float wfac = 1.0f - alpha + 1e-10f;
            float incl = wfac;
#pragma unroll
            for (int off = 1; off < 64; off <<= 1) {
                const float u = __shfl_up(incl, off);
                if (lane >= off) incl *= u;
            }
            float excl = __shfl_up(incl, 1);
            if (lane == 0) excl = 1.0f;
            const float al = alpha * excl;
            float pR = al * cr, pG = al * cg, pB = al * cb, pA = al;
#pragma unroll
            for (int off = 32; off; off >>= 1) {
                pR += __shfl_xor(pR, off);
                pG += __shfl_xor(pG, off);
                pB += __shfl_xor(pB, off);
                pA += __shfl_xor(pA, off);
            }
            const float Pc = __shfl(incl, 63);
            if (lane == 0) {
                sres[c][0] = pR;
                sres[c][1] = pG;
                sres[c][2] = pB;
                sres[c][3] = pA;
                sres[c][4] = Pc;
            }
        }
    }
    __syncthreads();
    if (threadIdx.x == 0) {
        float T = 1.0f, R = 0.f, G = 0.f, Bl = 0.f, A = 0.f;
#pragma unroll
        for (int c = 0; c < NCHUNK; ++c) {
            R += T * sres[c][0];
            G += T * sres[c][1];
            Bl += T * sres[c][2];
            A += T * sres[c][3];
            T *= sres[c][4];
        }
        const float bg = 1.0f - A;
        out[ray * 3 + 0] = R + bg;
        out[ray * 3 + 1] = G + bg;
        out[ray * 3 + 2] = Bl + bg;
    }
}

extern "C" void kernel_launch(void* const* d_in, const int* in_sizes, int n_in,
                              void* d_out, int out_size, void* d_ws, size_t ws_size,
                              hipStream_t stream) {
    const float* rays_o = (const float*)d_in[0];
    const float* rays_d = (const float*)d_in[1];
    const float* data = (const float*)d_in[2];
    float* out = (float*)d_out;
    const int B = in_sizes[0] / 3;

    const size_t need = (size_t)NVOX * 16;  // 32 MiB packed grid

    if (d_ws != nullptr && ws_size >= need) {
        uint4* gridp = (uint4*)d_ws;
        pack4_k<<<NVOX / 256, 256, 0, stream>>>(data, gridp);
        render4_k<true><<<B, 128, 0, stream>>>(rays_o, rays_d, (const void*)gridp, out, B);
    } else {
        render4_k<false><<<B, 128, 0, stream>>>(rays_o, rays_d, (const void*)data, out, B);
    }
}